// Round 11
// baseline (508.671 us; speedup 1.0000x reference)
//
#include <hip/hip_runtime.h>

typedef float floatx4_t __attribute__((ext_vector_type(4)));
typedef __bf16 bf16x8_t __attribute__((ext_vector_type(8)));
typedef short shortx8_t __attribute__((ext_vector_type(8)));
typedef unsigned long long ull;

__device__ __forceinline__ unsigned short f2bf_rne(float f) {
    unsigned u = __float_as_uint(f);
    unsigned r = u + 0x7FFFu + ((u >> 16) & 1u);
    return (unsigned short)(r >> 16);
}
__device__ __forceinline__ float bf2f(unsigned short h) {
    return __uint_as_float((unsigned)h << 16);
}

// bucket = col >> 6 (64 nodes); N=100000 -> B=1563.
#define MAXB 2048
#define CHUNK 4096    // r9/r10 scaling law: scatter is latency-bound; MORE blocks -> faster.
#define CAP 3072      // mean bucket size 2048; padding adds <=192; scatter clamps

// ---------------- K1: fused bucketed scatter + (x @ W1) gemm ----------------
// blocks [0,gC): scatter edges into packed[b*CAP+pos]; pass 1 stages packed entries in
//   LDS (no global re-read in pass 2); h/base merged into one cursor array.
// blocks [gC,gC+B): h1f[node] = (x @ W1)[node]  f32, UNSCALED (dis applied in sortdis)
// NOTE: no per-edge global atomics (round-5: +200 MB HBM writes).
__global__ __launch_bounds__(256) void k_scatter_gemm(const int* __restrict__ row,
                                                      const int* __restrict__ col,
                                                      const float* __restrict__ ew,
                                                      int* __restrict__ gcnt,
                                                      ull* __restrict__ packed,
                                                      const float* __restrict__ x,
                                                      const float* __restrict__ W1,
                                                      float* __restrict__ h1f,
                                                      int E, int B, int gC, int N) {
    int t = threadIdx.x;
    if ((int)blockIdx.x < gC) {
        // ---- scatter branch ----
        __shared__ int hb[MAXB];               // count -> then global cursor (merged h/base)
        __shared__ ull stage[CHUNK];           // 32 KB: packed entries built in pass 1
        __shared__ unsigned short sbuck[CHUNK];// 8 KB: bucket id per staged edge
        for (int i = t; i < B; i += 256) hb[i] = 0;
        __syncthreads();
        int cbase = blockIdx.x * CHUNK;
        int nloc = E - cbase; if (nloc > CHUNK) nloc = CHUNK;  // edges in this chunk
        // pass 1: load edges once, build packed entry into LDS, histogram
#pragma unroll 2
        for (int k = 0; k < 4; ++k) {
            int l = k * 1024 + t * 4;          // local edge index
            int e = cbase + l;
            if (e + 3 < E) {
                int4 c4 = *(const int4*)(col + e);
                int4 r4 = *(const int4*)(row + e);
                float4 w4 = *(const float4*)(ew + e);
                int cs[4] = {c4.x, c4.y, c4.z, c4.w};
                int rs[4] = {r4.x, r4.y, r4.z, r4.w};
                float wsv[4] = {w4.x, w4.y, w4.z, w4.w};
#pragma unroll
                for (int j = 0; j < 4; ++j) {
                    int c = cs[j];
                    int b = c >> 6;
                    atomicAdd(&hb[b], 1);
                    stage[l + j] = ((ull)(unsigned)((rs[j] << 6) | (c & 63)) << 32)
                                   | (unsigned)__float_as_uint(wsv[j]);
                    sbuck[l + j] = (unsigned short)b;
                }
            } else {
                for (int j = 0; j < 4; ++j) {
                    if (e + j < E) {
                        int c = col[e + j];
                        int b = c >> 6;
                        atomicAdd(&hb[b], 1);
                        stage[l + j] = ((ull)(unsigned)((row[e + j] << 6) | (c & 63)) << 32)
                                       | (unsigned)__float_as_uint(ew[e + j]);
                        sbuck[l + j] = (unsigned short)b;
                    }
                }
            }
        }
        __syncthreads();
        // reserve global ranges: hb[i] becomes the global cursor
        for (int i = t; i < B; i += 256) {
            int c = hb[i];
            hb[i] = c ? atomicAdd(&gcnt[i], c) : 0;
        }
        __syncthreads();
        // pass 2: LDS -> global scatter (no global edge re-read)
        for (int l = t; l < nloc; l += 256) {
            int b = sbuck[l];
            int pos = atomicAdd(&hb[b], 1);
            if (pos < CAP) packed[(size_t)b * CAP + pos] = stage[l];
        }
    } else {
        // ---- gemm branch: 4 waves x 16 nodes, MFMA 16x16x32 bf16, K=512 ----
        int b = blockIdx.x - gC;
        const int lane = t & 63;
        const int wave = t >> 6;
        const int m = lane & 15;
        const int q = lane >> 4;
        const int nbase = b * 64 + wave * 16;

        shortx8_t bs[16];
#pragma unroll
        for (int c = 0; c < 16; ++c) {
#pragma unroll
            for (int j = 0; j < 8; ++j) {
                int k = c * 32 + q * 8 + j;
                bs[c][j] = (short)f2bf_rne(W1[k * 16 + m]);
            }
        }

        int rowi = nbase + m;
        if (rowi >= N) rowi = N - 1;
        const float* xr = x + (size_t)rowi * 512;

        floatx4_t acc = {0.f, 0.f, 0.f, 0.f};
#pragma unroll
        for (int c = 0; c < 16; ++c) {
            const float4 u0 = *(const float4*)(xr + c * 32 + q * 8);
            const float4 u1 = *(const float4*)(xr + c * 32 + q * 8 + 4);
            shortx8_t as;
            as[0] = (short)f2bf_rne(u0.x); as[1] = (short)f2bf_rne(u0.y);
            as[2] = (short)f2bf_rne(u0.z); as[3] = (short)f2bf_rne(u0.w);
            as[4] = (short)f2bf_rne(u1.x); as[5] = (short)f2bf_rne(u1.y);
            as[6] = (short)f2bf_rne(u1.z); as[7] = (short)f2bf_rne(u1.w);
            acc = __builtin_amdgcn_mfma_f32_16x16x32_bf16(
                __builtin_bit_cast(bf16x8_t, as),
                __builtin_bit_cast(bf16x8_t, bs[c]), acc, 0, 0, 0);
        }

#pragma unroll
        for (int r = 0; r < 4; ++r) {
            int node = nbase + q * 4 + r;
            if (node < N)
                h1f[(size_t)node * 16 + m] = acc[r];
        }
    }
}

// ---------------- K2: LDS-staged counting sort with 4-ALIGNED PADDED segments ----------------
// Each node's packed2 segment starts at a multiple of 4 entries (16B) and is padded with
// zero entries (r=0,w=0 -> contributes exactly 0 to aggregation). Enables uint4 agg loads.
__global__ __launch_bounds__(256) void k_sortdis(const int* __restrict__ gcnt,
                                                 const ull* __restrict__ packed,
                                                 unsigned* __restrict__ packed2,
                                                 int2* __restrict__ rng,
                                                 float* __restrict__ dis,
                                                 const float* __restrict__ h1f,
                                                 unsigned short* __restrict__ h1s, int N) {
    __shared__ ull stage[CAP];        // 24 KB: bucket edges, staged once
    __shared__ unsigned s2[CAP];      // 12 KB: sorted (padded) entries
    __shared__ int cnt4[4][64];       // 4-way sharded counts
    __shared__ float dacc4[4][64];    // 4-way sharded weighted degree
    __shared__ int cur[64];
    __shared__ float sdis[64];
    __shared__ int stot;
    int t = threadIdx.x;
    int w4 = t >> 6;
    if (t < 64) {
#pragma unroll
        for (int s = 0; s < 4; ++s) { cnt4[s][t] = 0; dacc4[s][t] = 0.f; }
    }
    __syncthreads();
    int b = blockIdx.x;
    size_t gbase = (size_t)b * CAP;
    int szr = gcnt[b];
    int sz = szr < CAP ? szr : CAP;

    // stage bucket (one coalesced global read) + zero sort buffer
    for (int j = t; j < sz; j += 256) stage[j] = packed[gbase + j];
    for (int j = t; j < CAP; j += 256) s2[j] = 0u;
    __syncthreads();

    // pass 1 (LDS): per-node count + weighted degree, sharded by wave
    for (int j = t; j < sz; j += 256) {
        ull p = stage[j];
        int nd = (int)(p >> 32) & 63;
        atomicAdd(&cnt4[w4][nd], 1);
        atomicAdd(&dacc4[w4][nd], __uint_as_float((unsigned)p));
    }
    __syncthreads();
    if (t < 64) {
        int c = (cnt4[0][t] + cnt4[1][t]) + (cnt4[2][t] + cnt4[3][t]);
        float s = (dacc4[0][t] + dacc4[1][t]) + (dacc4[2][t] + dacc4[3][t]);
        int cpad = (c + 3) & ~3;  // pad segment to multiple of 4 entries
        int xp = cpad;
#pragma unroll
        for (int off = 1; off < 64; off <<= 1) {
            int y = __shfl_up(xp, off);
            if (t >= off) xp += y;
        }
        int off0 = xp - cpad;  // exclusive prefix of padded counts (4-aligned)
        cur[t] = off0;         // LDS-local offset
        if (t == 63) stot = xp;
        float d = (s > 0.f) ? rsqrtf(s) : 0.f;
        sdis[t] = d;
        int g = b * 64 + t;
        if (g < N) {
            int o0 = off0 < CAP ? off0 : CAP;       // overflow clamp (statistically never)
            int e1 = off0 + c; e1 = e1 < CAP ? e1 : CAP;
            rng[g] = make_int2((int)gbase + o0, (int)gbase + e1);
            dis[g] = d;
        }
    }
    __syncthreads();
    // pass 2 (LDS->LDS): counting-sort into padded slots
    for (int j = t; j < sz; j += 256) {
        ull p = stage[j];
        int hi = (int)(p >> 32);
        int nd = hi & 63;
        int r = hi >> 6;
        unsigned short wb = f2bf_rne(__uint_as_float((unsigned)p));  // sign bit 0
        int pos = atomicAdd(&cur[nd], 1);
        if (pos < CAP) s2[pos] = ((unsigned)r << 15) | (unsigned)wb;
    }
    __syncthreads();
    // flush padded extent: fully coalesced streaming store
    int szp = stot < CAP ? stot : CAP;
    for (int j = t; j < szp; j += 256) packed2[gbase + j] = s2[j];
    // epilogue: pre-scaled bf16 gather table (single rounding, same as round 0)
    for (int k = t; k < 1024; k += 256) {
        int n = k >> 4, f = k & 15;
        int node = b * 64 + n;
        if (node < N) {
            size_t idx = (size_t)node * 16 + f;
            h1s[idx] = f2bf_rne(sdis[n] * h1f[idx]);
        }
    }
}

// ---------------- agg1: one wave per node; uint4 edge loads (16B-aligned segments) ----------------
__global__ __launch_bounds__(256) void k_agg1(const int2* __restrict__ rng,
                                              const unsigned* __restrict__ packed2,
                                              const float* __restrict__ dis,
                                              const unsigned short* __restrict__ h1s,
                                              const float* __restrict__ b1,
                                              unsigned short* __restrict__ hs, int N) {
    int wv = (blockIdx.x * 256 + threadIdx.x) >> 6;  // node (wave-uniform)
    if (wv >= N) return;
    int lane = threadIdx.x & 63;
    int e4 = lane >> 4, f = lane & 15;
    int2 r2 = rng[wv];
    int beg = r2.x, end = r2.y;  // beg is 4-entry aligned; tail reads hit zero padding
    float a0 = 0.f, a1 = 0.f, a2 = 0.f, a3 = 0.f;
    for (int i = beg + e4 * 4; i < end; i += 16) {
        uint4 p4 = *(const uint4*)(packed2 + i);
        int r0 = p4.x >> 15, r1 = p4.y >> 15, r2i = p4.z >> 15, r3 = p4.w >> 15;
        a0 += __uint_as_float((p4.x & 0x7FFFu) << 16) * bf2f(h1s[(size_t)r0 * 16 + f]);
        a1 += __uint_as_float((p4.y & 0x7FFFu) << 16) * bf2f(h1s[(size_t)r1 * 16 + f]);
        a2 += __uint_as_float((p4.z & 0x7FFFu) << 16) * bf2f(h1s[(size_t)r2i * 16 + f]);
        a3 += __uint_as_float((p4.w & 0x7FFFu) << 16) * bf2f(h1s[(size_t)r3 * 16 + f]);
    }
    float a = (a0 + a1) + (a2 + a3);
    a += __shfl_xor(a, 16);
    a += __shfl_xor(a, 32);
    if (e4 == 0) {
        float dg = dis[wv];
        float v = dg * a + b1[f];
        v = (v > 0.f) ? v : 0.f;
        hs[(size_t)wv * 16 + f] = f2bf_rne(dg * v);  // pre-scaled for agg2
    }
}

// ---------------- agg2 fused with W2 + b2 + log_softmax ----------------
__global__ __launch_bounds__(256) void k_agg2out(const int2* __restrict__ rng,
                                                 const unsigned* __restrict__ packed2,
                                                 const float* __restrict__ dis,
                                                 const unsigned short* __restrict__ hs,
                                                 const float* __restrict__ W2,
                                                 const float* __restrict__ b2,
                                                 float* __restrict__ out, int N) {
    int wv = (blockIdx.x * 256 + threadIdx.x) >> 6;  // node (wave-uniform)
    if (wv >= N) return;
    int lane = threadIdx.x & 63;
    int e4 = lane >> 4, f = lane & 15;
    int2 r2 = rng[wv];
    int beg = r2.x, end = r2.y;
    float a0 = 0.f, a1 = 0.f, a2 = 0.f, a3 = 0.f;
    for (int i = beg + e4 * 4; i < end; i += 16) {
        uint4 p4 = *(const uint4*)(packed2 + i);
        int r0 = p4.x >> 15, r1 = p4.y >> 15, r2i = p4.z >> 15, r3 = p4.w >> 15;
        a0 += __uint_as_float((p4.x & 0x7FFFu) << 16) * bf2f(hs[(size_t)r0 * 16 + f]);
        a1 += __uint_as_float((p4.y & 0x7FFFu) << 16) * bf2f(hs[(size_t)r1 * 16 + f]);
        a2 += __uint_as_float((p4.z & 0x7FFFu) << 16) * bf2f(hs[(size_t)r2i * 16 + f]);
        a3 += __uint_as_float((p4.w & 0x7FFFu) << 16) * bf2f(hs[(size_t)r3 * 16 + f]);
    }
    float a = (a0 + a1) + (a2 + a3);
    a += __shfl_xor(a, 16);
    a += __shfl_xor(a, 32);
    // lane f (0..15) holds a[f]

    float dg = dis[wv];
    int c = lane;
    int cc = (c < 40) ? c : 39;  // clamp for safe loads
    float z = 0.f;
#pragma unroll
    for (int fi = 0; fi < 16; ++fi) {
        float af = __shfl(a, fi);
        z += af * W2[fi * 40 + cc];
    }
    z = dg * z + b2[cc];

    float zm = (c < 40) ? z : -3.4e38f;
#pragma unroll
    for (int off = 1; off < 64; off <<= 1) zm = fmaxf(zm, __shfl_xor(zm, off));
    float ex = (c < 40) ? __expf(z - zm) : 0.f;
    float s = ex;
#pragma unroll
    for (int off = 1; off < 64; off <<= 1) s += __shfl_xor(s, off);
    float lse = zm + __logf(s);
    if (c < 40) out[(size_t)wv * 40 + c] = z - lse;
}

extern "C" void kernel_launch(void* const* d_in, const int* in_sizes, int n_in,
                              void* d_out, int out_size, void* d_ws, size_t ws_size,
                              hipStream_t stream) {
    const float* x  = (const float*)d_in[0];
    const int*   ei = (const int*)d_in[1];
    const float* ew = (const float*)d_in[2];
    const float* W1 = (const float*)d_in[3];
    const float* b1 = (const float*)d_in[4];
    const float* W2 = (const float*)d_in[5];
    const float* b2 = (const float*)d_in[6];

    const int N = in_sizes[0] / 512;
    const int E = in_sizes[2];
    const int* row = ei;
    const int* col = ei + E;
    const int B = (N + 63) >> 6;  // buckets of 64 nodes
    const int Npad = B * 64;

    // workspace layout (~75 MB of ~800 MB)
    ull*      packed  = (ull*)d_ws;                            // B*CAP * 8B
    unsigned* packed2 = (unsigned*)(packed + (size_t)B * CAP); // B*CAP * 4B
    int*      gcnt    = (int*)(packed2 + (size_t)B * CAP);     // B
    int2*     rng     = (int2*)(gcnt + B + (B & 1));           // N (8B aligned)
    float*    dis     = (float*)(rng + N);                     // N
    float*    h1f     = dis + N;                               // 16*Npad f32 (unscaled gemm out)
    unsigned short* h1s = (unsigned short*)(h1f + (size_t)16 * Npad);  // 16*Npad bf16
    unsigned short* hs  = h1s + (size_t)16 * Npad;             // 16*Npad bf16

    hipMemsetAsync(gcnt, 0, (size_t)B * sizeof(int), stream);

    const int gC = (E + CHUNK - 1) / CHUNK;
    const int gW = (N * 64 + 255) / 256;  // one wave per node

    k_scatter_gemm<<<gC + B, 256, 0, stream>>>(row, col, ew, gcnt, packed,
                                               x, W1, h1f, E, B, gC, N);
    k_sortdis<<<B, 256, 0, stream>>>(gcnt, packed, packed2, rng, dis, h1f, h1s, N);
    k_agg1<<<gW, 256, 0, stream>>>(rng, packed2, dis, h1s, b1, hs, N);
    k_agg2out<<<gW, 256, 0, stream>>>(rng, packed2, dis, hs, W2, b2, (float*)d_out, N);
}

// Round 12
// 488.965 us; speedup vs baseline: 1.0403x; 1.0403x over previous
//
#include <hip/hip_runtime.h>

typedef float floatx4_t __attribute__((ext_vector_type(4)));
typedef __bf16 bf16x8_t __attribute__((ext_vector_type(8)));
typedef short shortx8_t __attribute__((ext_vector_type(8)));
typedef unsigned long long ull;

__device__ __forceinline__ unsigned short f2bf_rne(float f) {
    unsigned u = __float_as_uint(f);
    unsigned r = u + 0x7FFFu + ((u >> 16) & 1u);
    return (unsigned short)(r >> 16);
}
__device__ __forceinline__ float bf2f(unsigned short h) {
    return __uint_as_float((unsigned)h << 16);
}

// bucket = col >> 7 (128 nodes); N=100000 -> B2=782. Doubles scatter run length
// (42B->84B) to cut partial-line write amplification without touching parallelism.
#define MAXB2 1024
#define CHUNK 8192    // r9/r11 lessons: keep 391 scatter blocks; parallelism > traffic
#define CAP2 6144     // mean bucket 4096, +32 sigma; scatter clamps

// ---------------- K1: fused bucketed scatter + (x @ W1) gemm (r10 body, 128-buckets) ----
// blocks [0,gC): scatter edges into packed[b*CAP2+pos] = ((row<<7)|(col&127))<<32 | f32(w)
// blocks [gC,gC+Bg): h1f[node] = (x @ W1)[node]  f32, UNSCALED (dis applied in sortdis)
// NOTE: no per-edge global atomics (r5: +200 MB HBM); no big LDS staging (r11: occupancy).
__global__ __launch_bounds__(256) void k_scatter_gemm(const int* __restrict__ row,
                                                      const int* __restrict__ col,
                                                      const float* __restrict__ ew,
                                                      int* __restrict__ gcnt,
                                                      ull* __restrict__ packed,
                                                      const float* __restrict__ x,
                                                      const float* __restrict__ W1,
                                                      float* __restrict__ h1f,
                                                      int E, int B2, int gC, int N) {
    int t = threadIdx.x;
    if ((int)blockIdx.x < gC) {
        // ---- scatter branch ----
        __shared__ int h[MAXB2];
        __shared__ int base[MAXB2];
        for (int i = t; i < B2; i += 256) h[i] = 0;
        __syncthreads();
        int cbase = blockIdx.x * CHUNK;
#pragma unroll 2
        for (int k = 0; k < 8; ++k) {
            int e = cbase + k * 1024 + t * 4;
            if (e + 3 < E) {
                int4 c4 = *(const int4*)(col + e);
                atomicAdd(&h[c4.x >> 7], 1);
                atomicAdd(&h[c4.y >> 7], 1);
                atomicAdd(&h[c4.z >> 7], 1);
                atomicAdd(&h[c4.w >> 7], 1);
            } else {
                for (int j = 0; j < 4; ++j)
                    if (e + j < E) atomicAdd(&h[col[e + j] >> 7], 1);
            }
        }
        __syncthreads();
        for (int i = t; i < B2; i += 256) {
            int c = h[i];
            base[i] = c ? atomicAdd(&gcnt[i], c) : 0;
        }
        __syncthreads();
#pragma unroll 2
        for (int k = 0; k < 8; ++k) {
            int e = cbase + k * 1024 + t * 4;
            if (e + 3 < E) {
                int4 c4 = *(const int4*)(col + e);
                int4 r4 = *(const int4*)(row + e);
                float4 w4 = *(const float4*)(ew + e);
                int cs[4] = {c4.x, c4.y, c4.z, c4.w};
                int rs[4] = {r4.x, r4.y, r4.z, r4.w};
                float wsv[4] = {w4.x, w4.y, w4.z, w4.w};
#pragma unroll
                for (int j = 0; j < 4; ++j) {
                    int c = cs[j];
                    int b = c >> 7;
                    int pos = atomicAdd(&base[b], 1);
                    if (pos < CAP2) {
                        ull hi = (ull)(unsigned)((rs[j] << 7) | (c & 127)) << 32;
                        packed[(size_t)b * CAP2 + pos] = hi | (unsigned)__float_as_uint(wsv[j]);
                    }
                }
            } else {
                for (int j = 0; j < 4; ++j) {
                    if (e + j < E) {
                        int c = col[e + j];
                        int b = c >> 7;
                        int pos = atomicAdd(&base[b], 1);
                        if (pos < CAP2) {
                            ull hi = (ull)(unsigned)((row[e + j] << 7) | (c & 127)) << 32;
                            packed[(size_t)b * CAP2 + pos] = hi | (unsigned)__float_as_uint(ew[e + j]);
                        }
                    }
                }
            }
        }
    } else {
        // ---- gemm branch: 4 waves x 16 nodes, MFMA 16x16x32 bf16, K=512 (unchanged) ----
        int b = blockIdx.x - gC;
        const int lane = t & 63;
        const int wave = t >> 6;
        const int m = lane & 15;
        const int q = lane >> 4;
        const int nbase = b * 64 + wave * 16;

        shortx8_t bs[16];
#pragma unroll
        for (int c = 0; c < 16; ++c) {
#pragma unroll
            for (int j = 0; j < 8; ++j) {
                int k = c * 32 + q * 8 + j;
                bs[c][j] = (short)f2bf_rne(W1[k * 16 + m]);
            }
        }

        int rowi = nbase + m;
        if (rowi >= N) rowi = N - 1;
        const float* xr = x + (size_t)rowi * 512;

        floatx4_t acc = {0.f, 0.f, 0.f, 0.f};
#pragma unroll
        for (int c = 0; c < 16; ++c) {
            const float4 u0 = *(const float4*)(xr + c * 32 + q * 8);
            const float4 u1 = *(const float4*)(xr + c * 32 + q * 8 + 4);
            shortx8_t as;
            as[0] = (short)f2bf_rne(u0.x); as[1] = (short)f2bf_rne(u0.y);
            as[2] = (short)f2bf_rne(u0.z); as[3] = (short)f2bf_rne(u0.w);
            as[4] = (short)f2bf_rne(u1.x); as[5] = (short)f2bf_rne(u1.y);
            as[6] = (short)f2bf_rne(u1.z); as[7] = (short)f2bf_rne(u1.w);
            acc = __builtin_amdgcn_mfma_f32_16x16x32_bf16(
                __builtin_bit_cast(bf16x8_t, as),
                __builtin_bit_cast(bf16x8_t, bs[c]), acc, 0, 0, 0);
        }

#pragma unroll
        for (int r = 0; r < 4; ++r) {
            int node = nbase + q * 4 + r;
            if (node < N)
                h1f[(size_t)node * 16 + m] = acc[r];
        }
    }
}

// ---------------- K2: 128-node counting sort, 4-ALIGNED PADDED segments ----------------
// No LDS edge-staging (r8: neutral; packed is L2/L3-resident). 128-wide prefix via
// two per-wave scans + half-sum handoff. packed2[pos]=(r<<15)|bf15(w); h1s=bf16(dis*h1f).
__global__ __launch_bounds__(256) void k_sortdis(const int* __restrict__ gcnt,
                                                 const ull* __restrict__ packed,
                                                 unsigned* __restrict__ packed2,
                                                 int2* __restrict__ rng,
                                                 float* __restrict__ dis,
                                                 const float* __restrict__ h1f,
                                                 unsigned short* __restrict__ h1s, int N) {
    __shared__ unsigned s2[CAP2];     // 24 KB: sorted (padded) entries
    __shared__ int cnt4[4][128];      // 4-way sharded counts
    __shared__ float dacc4[4][128];   // 4-way sharded weighted degree
    __shared__ int cur[128];
    __shared__ float sdis[128];
    __shared__ int htot[2];           // per-half inclusive totals (padded)
    int t = threadIdx.x;
    int w4 = t >> 6;
    int lane = t & 63;
    if (t < 128) {
#pragma unroll
        for (int s = 0; s < 4; ++s) { cnt4[s][t] = 0; dacc4[s][t] = 0.f; }
    }
    for (int j = t; j < CAP2; j += 256) s2[j] = 0u;
    __syncthreads();
    int b = blockIdx.x;
    size_t gbase = (size_t)b * CAP2;
    int szr = gcnt[b];
    int sz = szr < CAP2 ? szr : CAP2;

    // pass 1: per-node count + weighted degree (global read; L2/L3-hot from scatter)
    for (int j = t; j < sz; j += 256) {
        ull p = packed[gbase + j];
        int nd = (int)(p >> 32) & 127;
        atomicAdd(&cnt4[w4][nd], 1);
        atomicAdd(&dacc4[w4][nd], __uint_as_float((unsigned)p));
    }
    __syncthreads();
    int c = 0, cpad = 0, xp = 0;
    float s = 0.f;
    if (t < 128) {
        c = (cnt4[0][t] + cnt4[1][t]) + (cnt4[2][t] + cnt4[3][t]);
        s = (dacc4[0][t] + dacc4[1][t]) + (dacc4[2][t] + dacc4[3][t]);
        cpad = (c + 3) & ~3;  // pad segment to multiple of 4 entries (16B align)
        xp = cpad;
#pragma unroll
        for (int off = 1; off < 64; off <<= 1) {
            int y = __shfl_up(xp, off);
            if (lane >= off) xp += y;
        }
        if (lane == 63) htot[t >> 6] = xp;  // inclusive total of this half
    }
    __syncthreads();
    if (t < 128) {
        int off0 = xp - cpad + ((t >= 64) ? htot[0] : 0);  // exclusive, 4-aligned
        cur[t] = off0;
        float d = (s > 0.f) ? rsqrtf(s) : 0.f;
        sdis[t] = d;
        int g = b * 128 + t;
        if (g < N) {
            int o0 = off0 < CAP2 ? off0 : CAP2;       // overflow clamp (statistically never)
            int e1 = off0 + c; e1 = e1 < CAP2 ? e1 : CAP2;
            rng[g] = make_int2((int)gbase + o0, (int)gbase + e1);
            dis[g] = d;
        }
    }
    __syncthreads();
    // pass 2: global re-read, counting-sort into padded LDS slots
    for (int j = t; j < sz; j += 256) {
        ull p = packed[gbase + j];
        int hi = (int)(p >> 32);
        int nd = hi & 127;
        int r = hi >> 7;
        unsigned short wb = f2bf_rne(__uint_as_float((unsigned)p));  // sign bit 0
        int pos = atomicAdd(&cur[nd], 1);
        if (pos < CAP2) s2[pos] = ((unsigned)r << 15) | (unsigned)wb;
    }
    __syncthreads();
    // flush padded extent: fully coalesced streaming store
    int stot = htot[0] + htot[1];
    int szp = stot < CAP2 ? stot : CAP2;
    for (int j = t; j < szp; j += 256) packed2[gbase + j] = s2[j];
    // epilogue: pre-scaled bf16 gather table (single rounding)
    for (int k = t; k < 2048; k += 256) {
        int n = k >> 4, f = k & 15;
        int node = b * 128 + n;
        if (node < N) {
            size_t idx = (size_t)node * 16 + f;
            h1s[idx] = f2bf_rne(sdis[n] * h1f[idx]);
        }
    }
}

// ---------------- agg1: one wave per node; uint4 edge loads (16B-aligned segments) ----------------
__global__ __launch_bounds__(256) void k_agg1(const int2* __restrict__ rng,
                                              const unsigned* __restrict__ packed2,
                                              const float* __restrict__ dis,
                                              const unsigned short* __restrict__ h1s,
                                              const float* __restrict__ b1,
                                              unsigned short* __restrict__ hs, int N) {
    int wv = (blockIdx.x * 256 + threadIdx.x) >> 6;  // node (wave-uniform)
    if (wv >= N) return;
    int lane = threadIdx.x & 63;
    int e4 = lane >> 4, f = lane & 15;
    int2 r2 = rng[wv];
    int beg = r2.x, end = r2.y;  // beg is 4-entry aligned; tail reads hit zero padding
    float a0 = 0.f, a1 = 0.f, a2 = 0.f, a3 = 0.f;
    for (int i = beg + e4 * 4; i < end; i += 16) {
        uint4 p4 = *(const uint4*)(packed2 + i);
        int r0 = p4.x >> 15, r1 = p4.y >> 15, r2i = p4.z >> 15, r3 = p4.w >> 15;
        a0 += __uint_as_float((p4.x & 0x7FFFu) << 16) * bf2f(h1s[(size_t)r0 * 16 + f]);
        a1 += __uint_as_float((p4.y & 0x7FFFu) << 16) * bf2f(h1s[(size_t)r1 * 16 + f]);
        a2 += __uint_as_float((p4.z & 0x7FFFu) << 16) * bf2f(h1s[(size_t)r2i * 16 + f]);
        a3 += __uint_as_float((p4.w & 0x7FFFu) << 16) * bf2f(h1s[(size_t)r3 * 16 + f]);
    }
    float a = (a0 + a1) + (a2 + a3);
    a += __shfl_xor(a, 16);
    a += __shfl_xor(a, 32);
    if (e4 == 0) {
        float dg = dis[wv];
        float v = dg * a + b1[f];
        v = (v > 0.f) ? v : 0.f;
        hs[(size_t)wv * 16 + f] = f2bf_rne(dg * v);  // pre-scaled for agg2
    }
}

// ---------------- agg2 fused with W2 + b2 + log_softmax ----------------
__global__ __launch_bounds__(256) void k_agg2out(const int2* __restrict__ rng,
                                                 const unsigned* __restrict__ packed2,
                                                 const float* __restrict__ dis,
                                                 const unsigned short* __restrict__ hs,
                                                 const float* __restrict__ W2,
                                                 const float* __restrict__ b2,
                                                 float* __restrict__ out, int N) {
    int wv = (blockIdx.x * 256 + threadIdx.x) >> 6;  // node (wave-uniform)
    if (wv >= N) return;
    int lane = threadIdx.x & 63;
    int e4 = lane >> 4, f = lane & 15;
    int2 r2 = rng[wv];
    int beg = r2.x, end = r2.y;
    float a0 = 0.f, a1 = 0.f, a2 = 0.f, a3 = 0.f;
    for (int i = beg + e4 * 4; i < end; i += 16) {
        uint4 p4 = *(const uint4*)(packed2 + i);
        int r0 = p4.x >> 15, r1 = p4.y >> 15, r2i = p4.z >> 15, r3 = p4.w >> 15;
        a0 += __uint_as_float((p4.x & 0x7FFFu) << 16) * bf2f(hs[(size_t)r0 * 16 + f]);
        a1 += __uint_as_float((p4.y & 0x7FFFu) << 16) * bf2f(hs[(size_t)r1 * 16 + f]);
        a2 += __uint_as_float((p4.z & 0x7FFFu) << 16) * bf2f(hs[(size_t)r2i * 16 + f]);
        a3 += __uint_as_float((p4.w & 0x7FFFu) << 16) * bf2f(hs[(size_t)r3 * 16 + f]);
    }
    float a = (a0 + a1) + (a2 + a3);
    a += __shfl_xor(a, 16);
    a += __shfl_xor(a, 32);
    // lane f (0..15) holds a[f]

    float dg = dis[wv];
    int c = lane;
    int cc = (c < 40) ? c : 39;  // clamp for safe loads
    float z = 0.f;
#pragma unroll
    for (int fi = 0; fi < 16; ++fi) {
        float af = __shfl(a, fi);
        z += af * W2[fi * 40 + cc];
    }
    z = dg * z + b2[cc];

    float zm = (c < 40) ? z : -3.4e38f;
#pragma unroll
    for (int off = 1; off < 64; off <<= 1) zm = fmaxf(zm, __shfl_xor(zm, off));
    float ex = (c < 40) ? __expf(z - zm) : 0.f;
    float s = ex;
#pragma unroll
    for (int off = 1; off < 64; off <<= 1) s += __shfl_xor(s, off);
    float lse = zm + __logf(s);
    if (c < 40) out[(size_t)wv * 40 + c] = z - lse;
}

extern "C" void kernel_launch(void* const* d_in, const int* in_sizes, int n_in,
                              void* d_out, int out_size, void* d_ws, size_t ws_size,
                              hipStream_t stream) {
    const float* x  = (const float*)d_in[0];
    const int*   ei = (const int*)d_in[1];
    const float* ew = (const float*)d_in[2];
    const float* W1 = (const float*)d_in[3];
    const float* b1 = (const float*)d_in[4];
    const float* W2 = (const float*)d_in[5];
    const float* b2 = (const float*)d_in[6];

    const int N = in_sizes[0] / 512;
    const int E = in_sizes[2];
    const int* row = ei;
    const int* col = ei + E;
    const int B2 = (N + 127) >> 7;   // 128-node buckets (scatter/sort)
    const int Bg = (N + 63) >> 6;    // 64-node gemm tiles
    const int Npad = Bg * 64;

    // workspace layout (~75 MB of ~800 MB)
    ull*      packed  = (ull*)d_ws;                             // B2*CAP2 * 8B
    unsigned* packed2 = (unsigned*)(packed + (size_t)B2 * CAP2);// B2*CAP2 * 4B
    int*      gcnt    = (int*)(packed2 + (size_t)B2 * CAP2);    // B2
    int2*     rng     = (int2*)(gcnt + B2 + (B2 & 1));          // N (8B aligned)
    float*    dis     = (float*)(rng + N);                      // N
    float*    h1f     = dis + N;                                // 16*Npad f32
    unsigned short* h1s = (unsigned short*)(h1f + (size_t)16 * Npad);  // 16*Npad bf16
    unsigned short* hs  = h1s + (size_t)16 * Npad;              // 16*Npad bf16

    hipMemsetAsync(gcnt, 0, (size_t)B2 * sizeof(int), stream);

    const int gC = (E + CHUNK - 1) / CHUNK;
    const int gW = (N * 64 + 255) / 256;  // one wave per node

    k_scatter_gemm<<<gC + Bg, 256, 0, stream>>>(row, col, ew, gcnt, packed,
                                                x, W1, h1f, E, B2, gC, N);
    k_sortdis<<<B2, 256, 0, stream>>>(gcnt, packed, packed2, rng, dis, h1f, h1s, N);
    k_agg1<<<gW, 256, 0, stream>>>(rng, packed2, dis, h1s, b1, hs, N);
    k_agg2out<<<gW, 256, 0, stream>>>(rng, packed2, dis, hs, W2, b2, (float*)d_out, N);
}